// Round 1
// baseline (660.833 us; speedup 1.0000x reference)
//
#include <hip/hip_runtime.h>
#include <hip/hip_cooperative_groups.h>
#include <math.h>

namespace cg = cooperative_groups;

#define NN 4096
#define DD 256
#define EPSV 1e-4f
#define STABV 1e-8f
#define AVAL (1.0f / 4096.0f)
#define BVAL (1.0f / 4096.0f)
#define MAX_IT 2000

// ---------------- init: zero accumulators ----------------
__global__ void sk_init_kernel(float* sumC, unsigned* flags, float* out) {
    if (threadIdx.x == 0) {
        sumC[0] = 0.0f;
        flags[0] = 0u;
        flags[1] = 0u;
        out[0] = 0.0f;   // cost accumulator (d_out is poisoned before every call)
    }
}

// ---------------- row norms of x and y ----------------
__global__ __launch_bounds__(64) void sk_norms_kernel(const float* __restrict__ x,
                                                      const float* __restrict__ y,
                                                      float* __restrict__ x2,
                                                      float* __restrict__ y2) {
    int row = blockIdx.x;                    // 0..2N-1
    const float* p = (row < NN) ? (x + (size_t)row * DD) : (y + (size_t)(row - NN) * DD);
    int lane = threadIdx.x;                  // 64
    float s = 0.0f;
#pragma unroll
    for (int c = 0; c < DD / 64; ++c) {
        float v = p[lane + c * 64];
        s += v * v;
    }
#pragma unroll
    for (int off = 32; off > 0; off >>= 1) s += __shfl_down(s, off, 64);
    if (lane == 0) {
        if (row < NN) x2[row] = s; else y2[row - NN] = s;
    }
}

// ---------------- GEMM: C = sqrt(max(x2_i + y2_j - 2 x·y, 0)); also sum(C) ----------------
__global__ __launch_bounds__(256) void sk_gemm_kernel(const float* __restrict__ x,
                                                      const float* __restrict__ y,
                                                      const float* __restrict__ x2,
                                                      const float* __restrict__ y2,
                                                      float* __restrict__ C,
                                                      float* __restrict__ sumC) {
    __shared__ float Xs[16][64];
    __shared__ float Ys[16][64];
    __shared__ float red[256];
    const int tid = threadIdx.x;
    const int tx = tid & 15, ty = tid >> 4;
    const int row0 = blockIdx.y * 64, col0 = blockIdx.x * 64;
    const int lr = tid >> 2;            // 0..63
    const int lk = (tid & 3) * 4;       // 0,4,8,12
    float acc[4][4];
#pragma unroll
    for (int a = 0; a < 4; ++a)
#pragma unroll
        for (int c = 0; c < 4; ++c) acc[a][c] = 0.0f;

    for (int k0 = 0; k0 < DD; k0 += 16) {
        float4 xa = *(const float4*)(x + (size_t)(row0 + lr) * DD + k0 + lk);
        float4 ya = *(const float4*)(y + (size_t)(col0 + lr) * DD + k0 + lk);
        __syncthreads();
        Xs[lk + 0][lr] = xa.x; Xs[lk + 1][lr] = xa.y; Xs[lk + 2][lr] = xa.z; Xs[lk + 3][lr] = xa.w;
        Ys[lk + 0][lr] = ya.x; Ys[lk + 1][lr] = ya.y; Ys[lk + 2][lr] = ya.z; Ys[lk + 3][lr] = ya.w;
        __syncthreads();
#pragma unroll
        for (int k = 0; k < 16; ++k) {
            float4 xv = *(const float4*)&Xs[k][ty * 4];
            float4 yv = *(const float4*)&Ys[k][tx * 4];
            float xr[4] = {xv.x, xv.y, xv.z, xv.w};
            float yr[4] = {yv.x, yv.y, yv.z, yv.w};
#pragma unroll
            for (int a = 0; a < 4; ++a)
#pragma unroll
                for (int c = 0; c < 4; ++c) acc[a][c] += xr[a] * yr[c];
        }
    }

    float lsum = 0.0f;
#pragma unroll
    for (int a = 0; a < 4; ++a) {
        int i = row0 + ty * 4 + a;
        float4 cv;
        float* cvp = (float*)&cv;
        float x2i = x2[i];
#pragma unroll
        for (int c = 0; c < 4; ++c) {
            int j = col0 + tx * 4 + c;
            float sq = x2i + y2[j] - 2.0f * acc[a][c];
            float cval = sqrtf(fmaxf(sq, 0.0f));
            cvp[c] = cval;
            lsum += cval;
        }
        *(float4*)(C + (size_t)i * NN + col0 + tx * 4) = cv;
    }
    red[tid] = lsum;
    __syncthreads();
    for (int off = 128; off > 0; off >>= 1) {
        if (tid < off) red[tid] += red[tid + off];
        __syncthreads();
    }
    if (tid == 0) atomicAdd(sumC, red[0]);
}

// ---------------- cooperative Sinkhorn loop + cost + outputs ----------------
// grid = 512 blocks x 256 threads (2 blocks/CU), bitwise-convergence early exit.
__global__ __launch_bounds__(256, 2) void sk_coop_kernel(const float* __restrict__ C,
                                                         float* __restrict__ u,
                                                         float* __restrict__ v,
                                                         float* __restrict__ s,
                                                         const float* __restrict__ sumC,
                                                         unsigned* __restrict__ flags,
                                                         float* __restrict__ out) {
    cg::grid_group grid = cg::this_grid();
    const int tid = threadIdx.x;
    const int bid = blockIdx.x;                 // 0..511
    const float mean = sumC[0] * (1.0f / ((float)NN * (float)NN));
    const float rs = 1.0f / (mean * EPSV);      // K = exp(-C_raw * rs)
    const float invMean = 1.0f / mean;
    const int wid = tid >> 6, lane = tid & 63;

    for (int it = 1; it <= MAX_IT; ++it) {
        // ---- Phase A: u = a / (K v + stab) ----
        if (it == 1) {
            // v0 == 0 by reference construction -> K@v0 == 0 exactly
            if (bid < 16) u[bid * 256 + tid] = AVAL / (0.0f + STABV);
        } else {
            int wg = bid * 4 + wid;             // 2048 waves, 2 rows each
#pragma unroll
            for (int rr = 0; rr < 2; ++rr) {
                int r = wg * 2 + rr;
                const float* Crow = C + (size_t)r * NN;
                float acc = 0.0f;
                for (int c = 0; c < NN / 64; ++c) {
                    int j = lane + c * 64;
                    acc += __expf(-Crow[j] * rs) * v[j];
                }
#pragma unroll
                for (int off = 32; off > 0; off >>= 1) acc += __shfl_down(acc, off, 64);
                if (lane == 0) {
                    float un = AVAL / (acc + STABV);
                    if (un != u[r]) atomicOr(&flags[it & 1], 1u);
                    u[r] = un;
                }
            }
        }
        if (bid < 16) s[bid * 256 + tid] = 0.0f;   // clear col accumulator for this iter
        grid.sync();

        // ---- Phase B: partial col sums of K^T u ----
        {
            int cs = bid & 15, rg = bid >> 4;       // 16 col stripes x 32 row groups
            int j = cs * 256 + tid;
            float acc = 0.0f;
            int i0 = rg * 128;
            for (int i = i0; i < i0 + 128; ++i)
                acc += __expf(-C[(size_t)i * NN + j] * rs) * u[i];
            atomicAdd(&s[j], acc);
        }
        grid.sync();

        // ---- Phase C: v = b / (K^T u + stab), convergence flag ----
        if (bid < 16) {
            int j = bid * 256 + tid;
            float vn = BVAL / (s[j] + STABV);
            if (it > 1 && vn != v[j]) atomicOr(&flags[it & 1], 1u);
            v[j] = vn;
        }
        if (bid == 0 && tid == 0) flags[(it + 1) & 1] = 0u;  // clear other-parity flag
        grid.sync();

        unsigned fl = __hip_atomic_load(&flags[it & 1], __ATOMIC_RELAXED, __HIP_MEMORY_SCOPE_AGENT);
        if (it > 1 && fl == 0u) break;   // bitwise fixed point: remaining iterations are identity
    }

    // ---- cost = sum_ij u_i * K_ij * v_j * (C_ij / mean) ----
    {
        __shared__ float red[256];
        int cs = bid & 15, rg = bid >> 4;
        int j = cs * 256 + tid;
        float vj = v[j];
        float acc = 0.0f;
        int i0 = rg * 128;
        for (int i = i0; i < i0 + 128; ++i) {
            float cr = C[(size_t)i * NN + j];
            float Kv = __expf(-cr * rs);
            acc += u[i] * Kv * vj * (cr * invMean);
        }
        red[tid] = acc;
        __syncthreads();
        for (int off = 128; off > 0; off >>= 1) {
            if (tid < off) red[tid] += red[tid + off];
            __syncthreads();
        }
        if (tid == 0) atomicAdd(&out[0], red[0]);
    }

    // ---- outputs: [cost, u(4096), v(4096)] ----
    if (bid < 16) {
        int j = bid * 256 + tid;
        out[1 + j] = u[j];
        out[1 + NN + j] = v[j];
    }
}

extern "C" void kernel_launch(void* const* d_in, const int* in_sizes, int n_in,
                              void* d_out, int out_size, void* d_ws, size_t ws_size,
                              hipStream_t stream) {
    const float* x = (const float*)d_in[0];
    const float* y = (const float*)d_in[1];
    float* out = (float*)d_out;
    float* wsf = (float*)d_ws;

    // ws layout (floats)
    float* C    = wsf;                           // N*N
    float* x2   = wsf + (size_t)NN * NN;         // N
    float* y2   = x2 + NN;                       // N
    float* u    = y2 + NN;                       // N
    float* v    = u + NN;                        // N
    float* s    = v + NN;                        // N
    float* sumC = s + NN;                        // 1
    unsigned* flags = (unsigned*)(sumC + 1);     // 2

    size_t need = ((size_t)NN * NN + 5 * NN + 8) * sizeof(float);
    if (ws_size < need) return;  // loud failure (poisoned outputs) rather than corruption

    sk_init_kernel<<<1, 64, 0, stream>>>(sumC, flags, out);
    sk_norms_kernel<<<dim3(2 * NN), dim3(64), 0, stream>>>(x, y, x2, y2);
    sk_gemm_kernel<<<dim3(NN / 64, NN / 64), dim3(256), 0, stream>>>(x, y, x2, y2, C, sumC);

    void* args[] = {(void*)&C, (void*)&u, (void*)&v, (void*)&s,
                    (void*)&sumC, (void*)&flags, (void*)&out};
    hipLaunchCooperativeKernel((void*)sk_coop_kernel, dim3(512), dim3(256), args, 0, stream);
}